// Round 9
// baseline (187.841 us; speedup 1.0000x reference)
//
#include <hip/hip_runtime.h>
#include <cstdint>
#include <cstddef>

#define TT  2048
#define HH  1024
#define FFN 2048
#define NL  4
#define BK  64
#define SK  2            // split-K for gemm2 (chunk = FFN/SK = 1024)

typedef __attribute__((ext_vector_type(8))) short bf16x8;
typedef __attribute__((ext_vector_type(4))) float f32x4;

__device__ __forceinline__ unsigned short f2bf(float f) {
  unsigned u = __builtin_bit_cast(unsigned, f);
  u += 0x7FFFu + ((u >> 16) & 1u);           // RNE
  return (unsigned short)(u >> 16);
}

__device__ __forceinline__ bf16x8 pack8(f32x4 f0, f32x4 f1) {
  bf16x8 v;
  v[0] = (short)f2bf(f0[0]); v[1] = (short)f2bf(f0[1]);
  v[2] = (short)f2bf(f0[2]); v[3] = (short)f2bf(f0[3]);
  v[4] = (short)f2bf(f1[0]); v[5] = (short)f2bf(f1[1]);
  v[6] = (short)f2bf(f1[2]); v[7] = (short)f2bf(f1[3]);
  return v;
}

// ---------------------------------------------------------------- zero
__global__ void k_zero(float* __restrict__ out, int* __restrict__ cnt) {
  int i = blockIdx.x * 256 + threadIdx.x;
  f32x4 z = {0.f, 0.f, 0.f, 0.f};
  reinterpret_cast<f32x4*>(out)[i] = z;
  if (i < NL) cnt[i] = 0;
}

// ---------------------------------------------------------------- routing lists
__global__ void k_build(const int* __restrict__ sel, const float* __restrict__ rw,
                        int* __restrict__ cnt, int* __restrict__ tok,
                        float* __restrict__ wgt) {
  int t = blockIdx.x * 256 + threadIdx.x;
  if (t >= TT) return;
  int   s0 = sel[t*4+0], s1 = sel[t*4+1], s2 = sel[t*4+2], s3 = sel[t*4+3];
  float r0 = rw[t*4+0],  r1 = rw[t*4+1],  r2 = rw[t*4+2],  r3 = rw[t*4+3];
#pragma unroll
  for (int i = 0; i < NL; ++i) {
    int eid = i * 8;
    float w = 0.f; bool m = false;
    if (s0 == eid) { w += r0; m = true; }
    if (s1 == eid) { w += r1; m = true; }
    if (s2 == eid) { w += r2; m = true; }
    if (s3 == eid) { w += r3; m = true; }
    if (m) {
      int p = atomicAdd(&cnt[i], 1);
      tok[i*TT + p] = t;
      wgt[i*TT + p] = w;
    }
  }
}

// ---------------------------------------------------------------- gather
__global__ void k_gather(const float* __restrict__ hidden, const int* __restrict__ cnt,
                         const int* __restrict__ tok, unsigned short* __restrict__ X) {
  int p = blockIdx.x, e = blockIdx.y;
  if (p >= cnt[e]) return;
  int t = tok[e*TT + p];
  const f32x4* src = reinterpret_cast<const f32x4*>(hidden + (size_t)t * HH);
  f32x4 a = src[threadIdx.x*2], b = src[threadIdx.x*2 + 1];
  reinterpret_cast<bf16x8*>(X + ((size_t)e*TT + p) * HH)[threadIdx.x] = pack8(a, b);
}

// ---------------------------------------------------------------- GEMM1
// 512 blocks, 512 thr = 8 waves. Whole B panel (16 gate + 16 up rows x K=1024)
// staged ONCE into 64 KB LDS (bf16, swizzled); ONE barrier; then each wave runs
// a fully-unrolled barrier-free K-loop: A reg-direct (L2), ds_read B, MFMA.
// 2 blocks/CU -> 16 waves/CU. Weights read exactly once per block.
__global__ __launch_bounds__(512, 4) void k_gemm1(
    const unsigned short* __restrict__ X, const float* __restrict__ gup,
    const int* __restrict__ cnt, unsigned short* __restrict__ Hb) {
  int bid = blockIdx.x;
  int xcd = bid & 7;
  int e   = xcd >> 1;
  int idx = (bid >> 3) * 2 + (xcd & 1);   // 0..127  N-tile
  int n0  = idx * 16;
  int c   = cnt[e];

  __shared__ alignas(16) unsigned short Bs[32 * HH];   // 64 KB

  int tid  = threadIdx.x;
  int lane = tid & 63, wv = tid >> 6;     // 8 waves
  int lr = lane & 15,  lk = lane >> 4;

  const unsigned short* Ab = X   + (size_t)e * TT * HH;
  const float*          Gb = gup + (size_t)e * 2 * FFN * HH;

  // ---- stage whole B panel: 32 rows x 1024 fp32 -> bf16 LDS (once)
  {
    int row = tid >> 4;                   // 0..31
    int fc  = (tid & 15) * 64;            // float col base (64 floats/thread)
    int grow = (row < 16) ? (n0 + row) : (FFN + n0 + row - 16);
    const float* src = Gb + (size_t)grow * HH + fc;
    int rx = (row & 7) << 4;
#pragma unroll
    for (int j = 0; j < 8; ++j) {
      f32x4 f0 = *(const f32x4*)(src + j*8);
      f32x4 f1 = *(const f32x4*)(src + j*8 + 4);
      int byteoff = fc*2 + j*16;
      *(bf16x8*)((char*)Bs + row*2048 + (byteoff ^ rx)) = pack8(f0, f1);
    }
  }
  __syncthreads();                        // the ONLY barrier

  int rxl = (lr & 7) << 4;                // read-side swizzle (row 16+lr same)

  for (int m0 = 0; m0 < c; m0 += 256) {
    const unsigned short* A0 = Ab + (size_t)(m0 + wv*32 + lr) * HH + lk*8;
    const unsigned short* A1 = A0 + (size_t)16 * HH;

    f32x4 accg0 = {0,0,0,0}, accg1 = {0,0,0,0};
    f32x4 accu0 = {0,0,0,0}, accu1 = {0,0,0,0};

#pragma unroll
    for (int t = 0; t < HH / BK; ++t) {   // 16 steps, barrier-free
      bf16x8 a00 = *(const bf16x8*)(A0 + t*BK);
      bf16x8 a01 = *(const bf16x8*)(A0 + t*BK + 32);
      bf16x8 a10 = *(const bf16x8*)(A1 + t*BK);
      bf16x8 a11 = *(const bf16x8*)(A1 + t*BK + 32);
      int cb0 = t*128 + lk*16;            // bf16 bytes within row
      int cb1 = cb0 + 64;
      const char* rg = (const char*)Bs + lr*2048;
      const char* ru = (const char*)Bs + (16 + lr)*2048;
      bf16x8 bg0 = *(const bf16x8*)(rg + (cb0 ^ rxl));
      bf16x8 bg1 = *(const bf16x8*)(rg + (cb1 ^ rxl));
      bf16x8 bu0 = *(const bf16x8*)(ru + (cb0 ^ rxl));
      bf16x8 bu1 = *(const bf16x8*)(ru + (cb1 ^ rxl));
      accg0 = __builtin_amdgcn_mfma_f32_16x16x32_bf16(a00, bg0, accg0, 0, 0, 0);
      accg0 = __builtin_amdgcn_mfma_f32_16x16x32_bf16(a01, bg1, accg0, 0, 0, 0);
      accg1 = __builtin_amdgcn_mfma_f32_16x16x32_bf16(a10, bg0, accg1, 0, 0, 0);
      accg1 = __builtin_amdgcn_mfma_f32_16x16x32_bf16(a11, bg1, accg1, 0, 0, 0);
      accu0 = __builtin_amdgcn_mfma_f32_16x16x32_bf16(a00, bu0, accu0, 0, 0, 0);
      accu0 = __builtin_amdgcn_mfma_f32_16x16x32_bf16(a01, bu1, accu0, 0, 0, 0);
      accu1 = __builtin_amdgcn_mfma_f32_16x16x32_bf16(a10, bu0, accu1, 0, 0, 0);
      accu1 = __builtin_amdgcn_mfma_f32_16x16x32_bf16(a11, bu1, accu1, 0, 0, 0);
    }

    // epilogue: silu(gate)*up -> bf16 Hb
#pragma unroll
    for (int j = 0; j < 4; ++j) {
      int p0 = m0 + wv*32 + lk*4 + j;
      if (p0 < c) {
        float gv = accg0[j];
        float hv = (gv / (1.f + __expf(-gv))) * accu0[j];
        Hb[((size_t)e * TT + p0) * FFN + (n0 + lr)] = f2bf(hv);
      }
      int p1 = p0 + 16;
      if (p1 < c) {
        float gv = accg1[j];
        float hv = (gv / (1.f + __expf(-gv))) * accu1[j];
        Hb[((size_t)e * TT + p1) * FFN + (n0 + lr)] = f2bf(hv);
      }
    }
  }
}

// ---------------------------------------------------------------- GEMM2
// Same template: B panel (16 rows x K=1024 chunk) staged once into 32 KB LDS,
// one barrier, barrier-free K-loop. SK=2, non-atomic partials.
__global__ __launch_bounds__(512, 4) void k_gemm2(
    const unsigned short* __restrict__ Hb, const float* __restrict__ down,
    const int* __restrict__ cnt, float* __restrict__ part) {
  int bid = blockIdx.x;
  int xcd = bid & 7;
  int e   = xcd >> 1;
  int idx = (bid >> 3) * 2 + (xcd & 1);   // 0..127
  int sk  = idx >> 6;                     // 0..1
  int n0  = (idx & 63) * 16;
  int c   = cnt[e];
  int kbase = sk * (FFN / SK);            // 0 or 1024

  __shared__ alignas(16) unsigned short Bs[16 * (FFN / SK)];   // 32 KB

  int tid  = threadIdx.x;
  int lane = tid & 63, wv = tid >> 6;
  int lr = lane & 15,  lk = lane >> 4;

  const unsigned short* Ab = Hb   + (size_t)e * TT * FFN;
  const float*          Db = down + (size_t)e * HH * FFN;

  // ---- stage B panel: 16 rows x 1024 fp32 -> bf16 LDS
  {
    int row = tid >> 5;                   // 0..15
    int fc  = (tid & 31) * 32;            // 32 floats/thread
    const float* src = Db + (size_t)(n0 + row) * FFN + kbase + fc;
    int rx = (row & 7) << 4;
#pragma unroll
    for (int j = 0; j < 4; ++j) {
      f32x4 f0 = *(const f32x4*)(src + j*8);
      f32x4 f1 = *(const f32x4*)(src + j*8 + 4);
      int byteoff = fc*2 + j*16;
      *(bf16x8*)((char*)Bs + row*2048 + (byteoff ^ rx)) = pack8(f0, f1);
    }
  }
  __syncthreads();

  int rxl = (lr & 7) << 4;
  float* pBase = part + (size_t)(sk * NL + e) * TT * HH;

  for (int m0 = 0; m0 < c; m0 += 256) {
    const unsigned short* A0 = Ab + (size_t)(m0 + wv*32 + lr) * FFN + kbase + lk*8;
    const unsigned short* A1 = A0 + (size_t)16 * FFN;

    f32x4 acc0 = {0,0,0,0}, acc1 = {0,0,0,0};

#pragma unroll
    for (int t = 0; t < (FFN / SK) / BK; ++t) {   // 16 steps
      bf16x8 a00 = *(const bf16x8*)(A0 + t*BK);
      bf16x8 a01 = *(const bf16x8*)(A0 + t*BK + 32);
      bf16x8 a10 = *(const bf16x8*)(A1 + t*BK);
      bf16x8 a11 = *(const bf16x8*)(A1 + t*BK + 32);
      int cb0 = t*128 + lk*16;
      int cb1 = cb0 + 64;
      const char* rb = (const char*)Bs + lr*2048;
      bf16x8 b0 = *(const bf16x8*)(rb + (cb0 ^ rxl));
      bf16x8 b1 = *(const bf16x8*)(rb + (cb1 ^ rxl));
      acc0 = __builtin_amdgcn_mfma_f32_16x16x32_bf16(a00, b0, acc0, 0, 0, 0);
      acc0 = __builtin_amdgcn_mfma_f32_16x16x32_bf16(a01, b1, acc0, 0, 0, 0);
      acc1 = __builtin_amdgcn_mfma_f32_16x16x32_bf16(a10, b0, acc1, 0, 0, 0);
      acc1 = __builtin_amdgcn_mfma_f32_16x16x32_bf16(a11, b1, acc1, 0, 0, 0);
    }

    // non-atomic partial store (single writer per element)
#pragma unroll
    for (int j = 0; j < 4; ++j) {
      int p0 = m0 + wv*32 + lk*4 + j;
      pBase[(size_t)p0 * HH + (n0 + lr)] = acc0[j];
      int p1 = p0 + 16;
      pBase[(size_t)p1 * HH + (n0 + lr)] = acc1[j];
    }
  }
}

// ---------------------------------------------------------------- combine
// 1024 blocks: sum SK slices, one atomicAdd per element, only p < c.
__global__ __launch_bounds__(256) void k_combine(
    const float* __restrict__ part, const int* __restrict__ cnt,
    const int* __restrict__ tok, const float* __restrict__ wgt,
    float* __restrict__ out) {
  int bid = blockIdx.x;
  int e   = bid >> 8;
  int ps  = bid & 255;
  int c   = cnt[e];
  int col = threadIdx.x * 4;
  const size_t skStride = (size_t)NL * TT * HH;

  for (int p = ps; p < c; p += 256) {
    int   t = tok[e*TT + p];
    float w = wgt[e*TT + p];
    const float* base = part + ((size_t)e * TT + p) * HH + col;
    f32x4 s = *(const f32x4*)(base);
    s += *(const f32x4*)(base + skStride);
    float* o = out + (size_t)t * HH + col;
    atomicAdd(o+0, w*s[0]); atomicAdd(o+1, w*s[1]);
    atomicAdd(o+2, w*s[2]); atomicAdd(o+3, w*s[3]);
  }
}

// ---------------------------------------------------------------- launch
extern "C" void kernel_launch(void* const* d_in, const int* in_sizes, int n_in,
                              void* d_out, int out_size, void* d_ws, size_t ws_size,
                              hipStream_t stream) {
  const float* hidden = (const float*)d_in[0];
  const int*   sel    = (const int*)d_in[1];
  const float* rw     = (const float*)d_in[2];
  const float* gup    = (const float*)d_in[3];
  const float* dwn    = (const float*)d_in[4];
  float* out = (float*)d_out;

  char* ws = (char*)d_ws;
  int*            cnt  = (int*)ws;                          // 1 KB pad
  int*            tok  = (int*)(ws + 1024);                 // 32 KB
  float*          wgt  = (float*)(ws + 33792);              // 32 KB
  unsigned short* X    = (unsigned short*)(ws + 66560);     // 16 MB
  unsigned short* Hb   = (unsigned short*)(ws + 16843776);  // 32 MB
  float*          part = (float*)(ws + 50398208);           // 64 MB

  k_zero   <<<2048, 256, 0, stream>>>(out, cnt);
  k_build  <<<8,    256, 0, stream>>>(sel, rw, cnt, tok, wgt);
  k_gather <<<dim3(TT, NL), 128, 0, stream>>>(hidden, cnt, tok, X);
  k_gemm1  <<<512, 512, 0, stream>>>(X, gup, cnt, Hb);
  k_gemm2  <<<512, 512, 0, stream>>>(Hb, dwn, cnt, part);
  k_combine<<<1024, 256, 0, stream>>>(part, cnt, tok, wgt, out);
}

// Round 10
// 68.110 us; speedup vs baseline: 2.7579x; 2.7579x over previous
//
#include <hip/hip_runtime.h>
#include <cstdint>
#include <cstddef>

#define TT  2048
#define HH  1024
#define FFN 2048
#define NL  4
#define BK  64
#define BM  256
#define SK  2            // split-K for gemm2 (chunk = FFN/SK = 1024)

typedef __attribute__((ext_vector_type(8))) short bf16x8;
typedef __attribute__((ext_vector_type(4))) unsigned short u16x4;
typedef __attribute__((ext_vector_type(4))) float f32x4;

__device__ __forceinline__ unsigned short f2bf(float f) {
  unsigned u = __builtin_bit_cast(unsigned, f);
  u += 0x7FFFu + ((u >> 16) & 1u);           // RNE
  return (unsigned short)(u >> 16);
}

__device__ __forceinline__ bf16x8 pack8(f32x4 f0, f32x4 f1) {
  bf16x8 v;
  v[0] = (short)f2bf(f0[0]); v[1] = (short)f2bf(f0[1]);
  v[2] = (short)f2bf(f0[2]); v[3] = (short)f2bf(f0[3]);
  v[4] = (short)f2bf(f1[0]); v[5] = (short)f2bf(f1[1]);
  v[6] = (short)f2bf(f1[2]); v[7] = (short)f2bf(f1[3]);
  return v;
}

__device__ __forceinline__ u16x4 pack4(f32x4 f0) {
  u16x4 v;
  v[0] = f2bf(f0[0]); v[1] = f2bf(f0[1]);
  v[2] = f2bf(f0[2]); v[3] = f2bf(f0[3]);
  return v;
}

__device__ __forceinline__ void async16(void* lds, const void* g) {
  __builtin_amdgcn_global_load_lds(
      (const __attribute__((address_space(1))) unsigned int*)g,
      (__attribute__((address_space(3))) unsigned int*)lds, 16, 0, 0);
}

// XOR swizzle inside [rows][64 bf16] (128 B rows); involution (rule 21).
__device__ __forceinline__ int swz(int b) { return b ^ (((b >> 7) & 7) << 4); }

// lgkm-only drain + raw barrier: counted global loads stay in flight (T4).
__device__ __forceinline__ void lds_barrier() {
  asm volatile("s_waitcnt lgkmcnt(0)" ::: "memory");
  __builtin_amdgcn_s_barrier();
}

// ---------------------------------------------------------------- zero
__global__ void k_zero(float* __restrict__ out, int* __restrict__ cnt) {
  int i = blockIdx.x * 256 + threadIdx.x;
  f32x4 z = {0.f, 0.f, 0.f, 0.f};
  reinterpret_cast<f32x4*>(out)[i] = z;
  if (i < NL) cnt[i] = 0;
}

// ---------------------------------------------------------------- routing lists
__global__ void k_build(const int* __restrict__ sel, const float* __restrict__ rw,
                        int* __restrict__ cnt, int* __restrict__ tok,
                        float* __restrict__ wgt) {
  int t = blockIdx.x * 256 + threadIdx.x;
  if (t >= TT) return;
  int   s0 = sel[t*4+0], s1 = sel[t*4+1], s2 = sel[t*4+2], s3 = sel[t*4+3];
  float r0 = rw[t*4+0],  r1 = rw[t*4+1],  r2 = rw[t*4+2],  r3 = rw[t*4+3];
#pragma unroll
  for (int i = 0; i < NL; ++i) {
    int eid = i * 8;
    float w = 0.f; bool m = false;
    if (s0 == eid) { w += r0; m = true; }
    if (s1 == eid) { w += r1; m = true; }
    if (s2 == eid) { w += r2; m = true; }
    if (s3 == eid) { w += r3; m = true; }
    if (m) {
      int p = atomicAdd(&cnt[i], 1);
      tok[i*TT + p] = t;
      wgt[i*TT + p] = w;
    }
  }
}

// ---------------------------------------------------------------- gather
__global__ void k_gather(const float* __restrict__ hidden, const int* __restrict__ cnt,
                         const int* __restrict__ tok, unsigned short* __restrict__ X) {
  int p = blockIdx.x, e = blockIdx.y;
  if (p >= cnt[e]) return;
  int t = tok[e*TT + p];
  const f32x4* src = reinterpret_cast<const f32x4*>(hidden + (size_t)t * HH);
  f32x4 a = src[threadIdx.x*2], b = src[threadIdx.x*2 + 1];
  reinterpret_cast<bf16x8*>(X + ((size_t)e*TT + p) * HH)[threadIdx.x] = pack8(a, b);
}

// ---------------------------------------------------------------- GEMM1
// R4 geometry + 2-deep counted pipeline. 256 blocks (1/CU), 512 thr = 8 waves
// (4M x 2N). BM=256, BN=32 dual (gate+up), BK=64. A: 3-buffer LDS ring via
// global_load_lds; B: reg prefetch distance 2. lgkm-only barrier keeps 2
// steps of global traffic in flight (counted vmcnt via B-reg dependence).
__global__ __launch_bounds__(512) void k_gemm1(
    const unsigned short* __restrict__ X, const float* __restrict__ gup,
    const int* __restrict__ cnt, unsigned short* __restrict__ Hb) {
  int bid = blockIdx.x;
  int xcd = bid & 7;
  int e   = xcd >> 1;
  int idx = (bid >> 3) * 2 + (xcd & 1);   // 0..63
  int n0  = idx * 32;
  int c   = cnt[e];

  __shared__ alignas(16) unsigned short As[3][BM*BK];   // 3 x 32 KB
  __shared__ alignas(16) unsigned short Bs[2][64*BK];   // 2 x 8 KB

  int tid  = threadIdx.x;
  int lane = tid & 63, wv = tid >> 6;     // 8 waves
  int lr = lane & 15,  lk = lane >> 4;
  int wm = wv >> 1,    wn = wv & 1;       // 4M x 2N

  const unsigned short* Ab = X   + (size_t)e * TT * HH;
  const float*          Gb = gup + (size_t)e * 2 * FFN * HH;

  // A staging: 32 KB = 32 chunks of 1 KB, 4/wave; linear dest, pre-swz src.
  int arow[4], acol[4], dstA[4];
#pragma unroll
  for (int cc = 0; cc < 4; ++cc) {
    int chunk = wv * 4 + cc;
    int P = chunk * 1024 + lane * 16;
    arow[cc] = P >> 7;
    acol[cc] = (P & 127) ^ ((arow[cc] & 7) << 4);
    dstA[cc] = P;
  }

  // B staging: 64 rows (32 gate + 32 up) x 64 k fp32; 8 floats/thread.
  int rb  = tid >> 3;                     // 0..63
  int cbf = (tid & 7) * 8;
  int grow = (rb < 32) ? (n0 + rb) : (FFN + n0 + rb - 32);
  const float* gB = Gb + (size_t)grow * HH + cbf;
  int wb = swz(rb * 128 + cbf * 2);

  int aoff[4][2], bgo[2], buo[2];
#pragma unroll
  for (int mi = 0; mi < 4; ++mi)
#pragma unroll
    for (int kk = 0; kk < 2; ++kk)
      aoff[mi][kk] = swz((wm*64 + mi*16 + lr) * 128 + kk*64 + lk*16);
#pragma unroll
  for (int kk = 0; kk < 2; ++kk) {
    bgo[kk] = swz((wn*16 + lr) * 128 + kk*64 + lk*16);
    buo[kk] = swz((32 + wn*16 + lr) * 128 + kk*64 + lk*16);
  }

  const int NT = HH / BK;   // 16

  for (int m0 = 0; m0 < c; m0 += BM) {
    __syncthreads();        // m0-iteration boundary: full drain (rare, 1 iter)

    const char* srcA[4];
#pragma unroll
    for (int cc = 0; cc < 4; ++cc)
      srcA[cc] = (const char*)(Ab + (size_t)(m0 + arow[cc]) * HH) + acol[cc];

    f32x4 accg[4], accu[4];
    f32x4 z = {0.f, 0.f, 0.f, 0.f};
#pragma unroll
    for (int a = 0; a < 4; ++a) { accg[a] = z; accu[a] = z; }

    f32x4 br[2][2];

    // ---- prologue: A(0)+B(0) issue; write B(0); A(1)+B(1) issue; barrier
#pragma unroll
    for (int cc = 0; cc < 4; ++cc) async16((char*)As[0] + dstA[cc], srcA[cc]);
    br[0][0] = *(const f32x4*)(gB);
    br[0][1] = *(const f32x4*)(gB + 4);
    *(bf16x8*)((char*)Bs[0] + wb) = pack8(br[0][0], br[0][1]);  // waits vmcnt -> A(0) landed too
#pragma unroll
    for (int cc = 0; cc < 4; ++cc) async16((char*)As[1] + dstA[cc], srcA[cc] + BK*2);
    br[1][0] = *(const f32x4*)(gB + BK);
    br[1][1] = *(const f32x4*)(gB + BK + 4);
    lds_barrier();

#pragma unroll
    for (int t = 0; t < NT; ++t) {
      // 1) issue step t+2 (A -> ring, B -> regs)
      if (t + 2 < NT) {
        int k2 = (t + 2) * BK;
#pragma unroll
        for (int cc = 0; cc < 4; ++cc)
          async16((char*)As[(t+2)%3] + dstA[cc], srcA[cc] + k2*2);
        br[t & 1][0] = *(const f32x4*)(gB + k2);
        br[t & 1][1] = *(const f32x4*)(gB + k2 + 4);
      }
      __builtin_amdgcn_sched_barrier(0);  // pin issues above the waiting ds_write
      // 2) ds_write B(t+1): counted vmcnt drains A(t+1)+B(t+1), keeps t+2 in flight
      if (t + 1 < NT)
        *(bf16x8*)((char*)Bs[(t+1) & 1] + wb) = pack8(br[(t+1) & 1][0], br[(t+1) & 1][1]);
      // 3) compute step t
      {
        const char* Asc = (const char*)As[t % 3];
        const char* Bsc = (const char*)Bs[t & 1];
#pragma unroll
        for (int kk = 0; kk < 2; ++kk) {
          bf16x8 bg = *(const bf16x8*)(Bsc + bgo[kk]);
          bf16x8 bu = *(const bf16x8*)(Bsc + buo[kk]);
#pragma unroll
          for (int mi = 0; mi < 4; ++mi) {
            bf16x8 a = *(const bf16x8*)(Asc + aoff[mi][kk]);
            accg[mi] = __builtin_amdgcn_mfma_f32_16x16x32_bf16(a, bg, accg[mi], 0, 0, 0);
            accu[mi] = __builtin_amdgcn_mfma_f32_16x16x32_bf16(a, bu, accu[mi], 0, 0, 0);
          }
        }
      }
      // 4) lgkm-only barrier (A(t+2)/B(t+2) stay in flight)
      if (t + 1 < NT) lds_barrier();
    }

    // epilogue: silu(gate)*up -> bf16 Hb
#pragma unroll
    for (int mi = 0; mi < 4; ++mi)
#pragma unroll
      for (int j = 0; j < 4; ++j) {
        int p = m0 + wm*64 + mi*16 + lk*4 + j;
        if (p < c) {
          float gv = accg[mi][j];
          float hv = (gv / (1.f + __expf(-gv))) * accu[mi][j];
          Hb[((size_t)e * TT + p) * FFN + (n0 + wn*16 + lr)] = f2bf(hv);
        }
      }
  }
}

// ---------------------------------------------------------------- GEMM2
// Same template. 256 blocks (1/CU), BM=256, BN=32, BK=64, SK=2.
// Non-atomic partial stores to part[sk][e][p][col].
__global__ __launch_bounds__(512) void k_gemm2(
    const unsigned short* __restrict__ Hb, const float* __restrict__ down,
    const int* __restrict__ cnt, float* __restrict__ part) {
  int bid = blockIdx.x;
  int xcd = bid & 7;
  int e   = xcd >> 1;
  int idx = (bid >> 3) * 2 + (xcd & 1);   // 0..63
  int sk  = idx >> 5;                     // 0..1
  int n0  = (idx & 31) * 32;
  int c   = cnt[e];
  int kbase = sk * (FFN / SK);            // 0 or 1024

  __shared__ alignas(16) unsigned short As[3][BM*BK];   // 3 x 32 KB
  __shared__ alignas(16) unsigned short Bs[2][32*BK];   // 2 x 4 KB

  int tid  = threadIdx.x;
  int lane = tid & 63, wv = tid >> 6;
  int lr = lane & 15,  lk = lane >> 4;
  int wm = wv >> 1,    wn = wv & 1;

  const unsigned short* Ab = Hb   + (size_t)e * TT * FFN;
  const float*          Db = down + (size_t)e * HH * FFN;

  int arow[4], acol[4], dstA[4];
#pragma unroll
  for (int cc = 0; cc < 4; ++cc) {
    int chunk = wv * 4 + cc;
    int P = chunk * 1024 + lane * 16;
    arow[cc] = P >> 7;
    acol[cc] = (P & 127) ^ ((arow[cc] & 7) << 4);
    dstA[cc] = P;
  }

  // B staging: 32 rows x 64 k fp32; 4 floats/thread.
  int rb  = tid >> 4;                     // 0..31
  int cbf = (tid & 15) * 4;
  const float* gB = Db + (size_t)(n0 + rb) * FFN + kbase + cbf;
  int wb = swz(rb * 128 + cbf * 2);

  int aoff[4][2], boff[2];
#pragma unroll
  for (int mi = 0; mi < 4; ++mi)
#pragma unroll
    for (int kk = 0; kk < 2; ++kk)
      aoff[mi][kk] = swz((wm*64 + mi*16 + lr) * 128 + kk*64 + lk*16);
#pragma unroll
  for (int kk = 0; kk < 2; ++kk)
    boff[kk] = swz((wn*16 + lr) * 128 + kk*64 + lk*16);

  float* pBase = part + (size_t)(sk * NL + e) * TT * HH;
  const int NT = (FFN / SK) / BK;   // 16

  for (int m0 = 0; m0 < c; m0 += BM) {
    __syncthreads();

    const char* srcA[4];
#pragma unroll
    for (int cc = 0; cc < 4; ++cc)
      srcA[cc] = (const char*)(Ab + (size_t)(m0 + arow[cc]) * FFN + kbase) + acol[cc];

    f32x4 acc[4];
    f32x4 z = {0.f, 0.f, 0.f, 0.f};
#pragma unroll
    for (int a = 0; a < 4; ++a) acc[a] = z;

    f32x4 br[2];

    // ---- prologue
#pragma unroll
    for (int cc = 0; cc < 4; ++cc) async16((char*)As[0] + dstA[cc], srcA[cc]);
    br[0] = *(const f32x4*)(gB);
    *(u16x4*)((char*)Bs[0] + wb) = pack4(br[0]);
#pragma unroll
    for (int cc = 0; cc < 4; ++cc) async16((char*)As[1] + dstA[cc], srcA[cc] + BK*2);
    br[1] = *(const f32x4*)(gB + BK);
    lds_barrier();

#pragma unroll
    for (int t = 0; t < NT; ++t) {
      if (t + 2 < NT) {
        int k2 = (t + 2) * BK;
#pragma unroll
        for (int cc = 0; cc < 4; ++cc)
          async16((char*)As[(t+2)%3] + dstA[cc], srcA[cc] + k2*2);
        br[t & 1] = *(const f32x4*)(gB + k2);
      }
      __builtin_amdgcn_sched_barrier(0);
      if (t + 1 < NT)
        *(u16x4*)((char*)Bs[(t+1) & 1] + wb) = pack4(br[(t+1) & 1]);
      {
        const char* Asc = (const char*)As[t % 3];
        const char* Bsc = (const char*)Bs[t & 1];
#pragma unroll
        for (int kk = 0; kk < 2; ++kk) {
          bf16x8 bf_ = *(const bf16x8*)(Bsc + boff[kk]);
#pragma unroll
          for (int mi = 0; mi < 4; ++mi) {
            bf16x8 a = *(const bf16x8*)(Asc + aoff[mi][kk]);
            acc[mi] = __builtin_amdgcn_mfma_f32_16x16x32_bf16(a, bf_, acc[mi], 0, 0, 0);
          }
        }
      }
      if (t + 1 < NT) lds_barrier();
    }

    // non-atomic partial store (single writer per element)
#pragma unroll
    for (int mi = 0; mi < 4; ++mi)
#pragma unroll
      for (int j = 0; j < 4; ++j) {
        int p = m0 + wm*64 + mi*16 + lk*4 + j;
        pBase[(size_t)p * HH + (n0 + wn*16 + lr)] = acc[mi][j];
      }
  }
}

// ---------------------------------------------------------------- combine
__global__ __launch_bounds__(256) void k_combine(
    const float* __restrict__ part, const int* __restrict__ cnt,
    const int* __restrict__ tok, const float* __restrict__ wgt,
    float* __restrict__ out) {
  int bid = blockIdx.x;
  int e   = bid >> 8;
  int ps  = bid & 255;
  int c   = cnt[e];
  int col = threadIdx.x * 4;
  const size_t skStride = (size_t)NL * TT * HH;

  for (int p = ps; p < c; p += 256) {
    int   t = tok[e*TT + p];
    float w = wgt[e*TT + p];
    const float* base = part + ((size_t)e * TT + p) * HH + col;
    f32x4 s = *(const f32x4*)(base);
    s += *(const f32x4*)(base + skStride);
    float* o = out + (size_t)t * HH + col;
    atomicAdd(o+0, w*s[0]); atomicAdd(o+1, w*s[1]);
    atomicAdd(o+2, w*s[2]); atomicAdd(o+3, w*s[3]);
  }
}

// ---------------------------------------------------------------- launch
extern "C" void kernel_launch(void* const* d_in, const int* in_sizes, int n_in,
                              void* d_out, int out_size, void* d_ws, size_t ws_size,
                              hipStream_t stream) {
  const float* hidden = (const float*)d_in[0];
  const int*   sel    = (const int*)d_in[1];
  const float* rw     = (const float*)d_in[2];
  const float* gup    = (const float*)d_in[3];
  const float* dwn    = (const float*)d_in[4];
  float* out = (float*)d_out;

  char* ws = (char*)d_ws;
  int*            cnt  = (int*)ws;                          // 1 KB pad
  int*            tok  = (int*)(ws + 1024);                 // 32 KB
  float*          wgt  = (float*)(ws + 33792);              // 32 KB
  unsigned short* X    = (unsigned short*)(ws + 66560);     // 16 MB
  unsigned short* Hb   = (unsigned short*)(ws + 16843776);  // 32 MB
  float*          part = (float*)(ws + 50398208);           // 64 MB

  k_zero   <<<2048, 256, 0, stream>>>(out, cnt);
  k_build  <<<8,    256, 0, stream>>>(sel, rw, cnt, tok, wgt);
  k_gather <<<dim3(TT, NL), 128, 0, stream>>>(hidden, cnt, tok, X);
  k_gemm1  <<<256, 512, 0, stream>>>(X, gup, cnt, Hb);
  k_gemm2  <<<256, 512, 0, stream>>>(Hb, dwn, cnt, part);
  k_combine<<<1024, 256, 0, stream>>>(part, cnt, tok, wgt, out);
}

// Round 11
// 61.693 us; speedup vs baseline: 3.0448x; 1.1040x over previous
//
#include <hip/hip_runtime.h>
#include <cstdint>
#include <cstddef>

#define TT  2048
#define HH  1024
#define FFN 2048
#define NL  4
#define BK  64
#define BM  256

typedef __attribute__((ext_vector_type(8))) short bf16x8;
typedef __attribute__((ext_vector_type(4))) unsigned short u16x4;
typedef __attribute__((ext_vector_type(4))) float f32x4;
typedef __attribute__((ext_vector_type(2))) float f32x2;

__device__ __forceinline__ unsigned short f2bf(float f) {
  unsigned u = __builtin_bit_cast(unsigned, f);
  u += 0x7FFFu + ((u >> 16) & 1u);           // RNE
  return (unsigned short)(u >> 16);
}

__device__ __forceinline__ bf16x8 pack8(f32x4 f0, f32x4 f1) {
  bf16x8 v;
  v[0] = (short)f2bf(f0[0]); v[1] = (short)f2bf(f0[1]);
  v[2] = (short)f2bf(f0[2]); v[3] = (short)f2bf(f0[3]);
  v[4] = (short)f2bf(f1[0]); v[5] = (short)f2bf(f1[1]);
  v[6] = (short)f2bf(f1[2]); v[7] = (short)f2bf(f1[3]);
  return v;
}

__device__ __forceinline__ unsigned pack2(f32x2 f) {
  return (unsigned)f2bf(f[0]) | ((unsigned)f2bf(f[1]) << 16);
}

__device__ __forceinline__ void async16(void* lds, const void* g) {
  __builtin_amdgcn_global_load_lds(
      (const __attribute__((address_space(1))) unsigned int*)g,
      (__attribute__((address_space(3))) unsigned int*)lds, 16, 0, 0);
}

// XOR swizzle inside [rows][64 bf16] (128 B rows); involution (rule 21).
__device__ __forceinline__ int swz(int b) { return b ^ (((b >> 7) & 7) << 4); }

// lgkm-only drain + raw barrier: counted global loads stay in flight (T4).
__device__ __forceinline__ void lds_barrier() {
  asm volatile("s_waitcnt lgkmcnt(0)" ::: "memory");
  __builtin_amdgcn_s_barrier();
}

// ---------------------------------------------------------------- zero
__global__ void k_zero(float* __restrict__ out, int* __restrict__ cnt) {
  int i = blockIdx.x * 256 + threadIdx.x;
  f32x4 z = {0.f, 0.f, 0.f, 0.f};
  reinterpret_cast<f32x4*>(out)[i] = z;
  if (i < NL) cnt[i] = 0;
}

// ---------------------------------------------------------------- routing lists
__global__ void k_build(const int* __restrict__ sel, const float* __restrict__ rw,
                        int* __restrict__ cnt, int* __restrict__ tok,
                        float* __restrict__ wgt) {
  int t = blockIdx.x * 256 + threadIdx.x;
  if (t >= TT) return;
  int   s0 = sel[t*4+0], s1 = sel[t*4+1], s2 = sel[t*4+2], s3 = sel[t*4+3];
  float r0 = rw[t*4+0],  r1 = rw[t*4+1],  r2 = rw[t*4+2],  r3 = rw[t*4+3];
#pragma unroll
  for (int i = 0; i < NL; ++i) {
    int eid = i * 8;
    float w = 0.f; bool m = false;
    if (s0 == eid) { w += r0; m = true; }
    if (s1 == eid) { w += r1; m = true; }
    if (s2 == eid) { w += r2; m = true; }
    if (s3 == eid) { w += r3; m = true; }
    if (m) {
      int p = atomicAdd(&cnt[i], 1);
      tok[i*TT + p] = t;
      wgt[i*TT + p] = w;
    }
  }
}

// ---------------------------------------------------------------- gather
__global__ void k_gather(const float* __restrict__ hidden, const int* __restrict__ cnt,
                         const int* __restrict__ tok, unsigned short* __restrict__ X) {
  int p = blockIdx.x, e = blockIdx.y;
  if (p >= cnt[e]) return;
  int t = tok[e*TT + p];
  const f32x4* src = reinterpret_cast<const f32x4*>(hidden + (size_t)t * HH);
  f32x4 a = src[threadIdx.x*2], b = src[threadIdx.x*2 + 1];
  reinterpret_cast<bf16x8*>(X + ((size_t)e*TT + p) * HH)[threadIdx.x] = pack8(a, b);
}

// ---------------------------------------------------------------- GEMM1
// UNCHANGED from R10 (best). 256 blocks (1/CU), 512 thr = 8 waves (4M x 2N).
// BM=256, BN=32 dual (gate+up), BK=64. A: 3-buffer LDS ring via
// global_load_lds; B: reg prefetch distance 2; lgkm-only barriers.
__global__ __launch_bounds__(512) void k_gemm1(
    const unsigned short* __restrict__ X, const float* __restrict__ gup,
    const int* __restrict__ cnt, unsigned short* __restrict__ Hb) {
  int bid = blockIdx.x;
  int xcd = bid & 7;
  int e   = xcd >> 1;
  int idx = (bid >> 3) * 2 + (xcd & 1);   // 0..63
  int n0  = idx * 32;
  int c   = cnt[e];

  __shared__ alignas(16) unsigned short As[3][BM*BK];   // 3 x 32 KB
  __shared__ alignas(16) unsigned short Bs[2][64*BK];   // 2 x 8 KB

  int tid  = threadIdx.x;
  int lane = tid & 63, wv = tid >> 6;     // 8 waves
  int lr = lane & 15,  lk = lane >> 4;
  int wm = wv >> 1,    wn = wv & 1;       // 4M x 2N

  const unsigned short* Ab = X   + (size_t)e * TT * HH;
  const float*          Gb = gup + (size_t)e * 2 * FFN * HH;

  int arow[4], acol[4], dstA[4];
#pragma unroll
  for (int cc = 0; cc < 4; ++cc) {
    int chunk = wv * 4 + cc;
    int P = chunk * 1024 + lane * 16;
    arow[cc] = P >> 7;
    acol[cc] = (P & 127) ^ ((arow[cc] & 7) << 4);
    dstA[cc] = P;
  }

  int rb  = tid >> 3;                     // 0..63
  int cbf = (tid & 7) * 8;
  int grow = (rb < 32) ? (n0 + rb) : (FFN + n0 + rb - 32);
  const float* gB = Gb + (size_t)grow * HH + cbf;
  int wb = swz(rb * 128 + cbf * 2);

  int aoff[4][2], bgo[2], buo[2];
#pragma unroll
  for (int mi = 0; mi < 4; ++mi)
#pragma unroll
    for (int kk = 0; kk < 2; ++kk)
      aoff[mi][kk] = swz((wm*64 + mi*16 + lr) * 128 + kk*64 + lk*16);
#pragma unroll
  for (int kk = 0; kk < 2; ++kk) {
    bgo[kk] = swz((wn*16 + lr) * 128 + kk*64 + lk*16);
    buo[kk] = swz((32 + wn*16 + lr) * 128 + kk*64 + lk*16);
  }

  const int NT = HH / BK;   // 16

  for (int m0 = 0; m0 < c; m0 += BM) {
    __syncthreads();

    const char* srcA[4];
#pragma unroll
    for (int cc = 0; cc < 4; ++cc)
      srcA[cc] = (const char*)(Ab + (size_t)(m0 + arow[cc]) * HH) + acol[cc];

    f32x4 accg[4], accu[4];
    f32x4 z = {0.f, 0.f, 0.f, 0.f};
#pragma unroll
    for (int a = 0; a < 4; ++a) { accg[a] = z; accu[a] = z; }

    f32x4 br[2][2];

#pragma unroll
    for (int cc = 0; cc < 4; ++cc) async16((char*)As[0] + dstA[cc], srcA[cc]);
    br[0][0] = *(const f32x4*)(gB);
    br[0][1] = *(const f32x4*)(gB + 4);
    *(bf16x8*)((char*)Bs[0] + wb) = pack8(br[0][0], br[0][1]);
#pragma unroll
    for (int cc = 0; cc < 4; ++cc) async16((char*)As[1] + dstA[cc], srcA[cc] + BK*2);
    br[1][0] = *(const f32x4*)(gB + BK);
    br[1][1] = *(const f32x4*)(gB + BK + 4);
    lds_barrier();

#pragma unroll
    for (int t = 0; t < NT; ++t) {
      if (t + 2 < NT) {
        int k2 = (t + 2) * BK;
#pragma unroll
        for (int cc = 0; cc < 4; ++cc)
          async16((char*)As[(t+2)%3] + dstA[cc], srcA[cc] + k2*2);
        br[t & 1][0] = *(const f32x4*)(gB + k2);
        br[t & 1][1] = *(const f32x4*)(gB + k2 + 4);
      }
      __builtin_amdgcn_sched_barrier(0);
      if (t + 1 < NT)
        *(bf16x8*)((char*)Bs[(t+1) & 1] + wb) = pack8(br[(t+1) & 1][0], br[(t+1) & 1][1]);
      {
        const char* Asc = (const char*)As[t % 3];
        const char* Bsc = (const char*)Bs[t & 1];
#pragma unroll
        for (int kk = 0; kk < 2; ++kk) {
          bf16x8 bg = *(const bf16x8*)(Bsc + bgo[kk]);
          bf16x8 bu = *(const bf16x8*)(Bsc + buo[kk]);
#pragma unroll
          for (int mi = 0; mi < 4; ++mi) {
            bf16x8 a = *(const bf16x8*)(Asc + aoff[mi][kk]);
            accg[mi] = __builtin_amdgcn_mfma_f32_16x16x32_bf16(a, bg, accg[mi], 0, 0, 0);
            accu[mi] = __builtin_amdgcn_mfma_f32_16x16x32_bf16(a, bu, accu[mi], 0, 0, 0);
          }
        }
      }
      if (t + 1 < NT) lds_barrier();
    }

#pragma unroll
    for (int mi = 0; mi < 4; ++mi)
#pragma unroll
      for (int j = 0; j < 4; ++j) {
        int p = m0 + wm*64 + mi*16 + lk*4 + j;
        if (p < c) {
          float gv = accg[mi][j];
          float hv = (gv / (1.f + __expf(-gv))) * accu[mi][j];
          Hb[((size_t)e * TT + p) * FFN + (n0 + wn*16 + lr)] = f2bf(hv);
        }
      }
  }
}

// ---------------------------------------------------------------- GEMM2
// SK=1, BN=16, 256 blocks (1/CU), 512 thr = 8 waves (all-M). K=FFN (nt=32),
// same 3-buffer ring + reg-B pipeline. Epilogue: direct atomicAdd of
// w * acc into out (1M scalar atomics; no part buffer, no combine).
__global__ __launch_bounds__(512) void k_gemm2(
    const unsigned short* __restrict__ Hb, const float* __restrict__ down,
    const int* __restrict__ cnt, const int* __restrict__ tok,
    const float* __restrict__ wgt, float* __restrict__ out) {
  int bid = blockIdx.x;
  int xcd = bid & 7;
  int e   = xcd >> 1;
  int idx = (bid >> 3) * 2 + (xcd & 1);   // 0..63
  int n0  = idx * 16;
  int c   = cnt[e];

  __shared__ alignas(16) unsigned short As[3][BM*BK];   // 3 x 32 KB
  __shared__ alignas(16) unsigned short Bs[2][16*BK];   // 2 x 2 KB

  int tid  = threadIdx.x;
  int lane = tid & 63, wv = tid >> 6;     // 8 waves, all M
  int lr = lane & 15,  lk = lane >> 4;

  const unsigned short* Ab = Hb   + (size_t)e * TT * FFN;
  const float*          Db = down + (size_t)e * HH * FFN;

  int arow[4], acol[4], dstA[4];
#pragma unroll
  for (int cc = 0; cc < 4; ++cc) {
    int chunk = wv * 4 + cc;
    int P = chunk * 1024 + lane * 16;
    arow[cc] = P >> 7;
    acol[cc] = (P & 127) ^ ((arow[cc] & 7) << 4);
    dstA[cc] = P;
  }

  // B staging: 16 rows x 64 k fp32 = 4 KB/step; 2 floats/thread.
  int rb = tid >> 5;                      // 0..15
  int cw = tid & 31;                      // 2-float granule
  const float* gB = Db + (size_t)(n0 + rb) * FFN + cw*2;
  int wb = swz(rb * 128 + cw * 4);

  int aoff[2][2], boff[2];
#pragma unroll
  for (int mi = 0; mi < 2; ++mi)
#pragma unroll
    for (int kk = 0; kk < 2; ++kk)
      aoff[mi][kk] = swz((wv*32 + mi*16 + lr) * 128 + kk*64 + lk*16);
#pragma unroll
  for (int kk = 0; kk < 2; ++kk)
    boff[kk] = swz((lr) * 128 + kk*64 + lk*16);

  const int NT = FFN / BK;   // 32

  for (int m0 = 0; m0 < c; m0 += BM) {
    __syncthreads();

    const char* srcA[4];
#pragma unroll
    for (int cc = 0; cc < 4; ++cc)
      srcA[cc] = (const char*)(Ab + (size_t)(m0 + arow[cc]) * FFN) + acol[cc];

    f32x4 acc[2];
    f32x4 z = {0.f, 0.f, 0.f, 0.f};
    acc[0] = z; acc[1] = z;

    f32x2 br[2];

    // prologue
#pragma unroll
    for (int cc = 0; cc < 4; ++cc) async16((char*)As[0] + dstA[cc], srcA[cc]);
    br[0] = *(const f32x2*)(gB);
    *(unsigned*)((char*)Bs[0] + wb) = pack2(br[0]);
#pragma unroll
    for (int cc = 0; cc < 4; ++cc) async16((char*)As[1] + dstA[cc], srcA[cc] + BK*2);
    br[1] = *(const f32x2*)(gB + BK);
    lds_barrier();

#pragma unroll
    for (int t = 0; t < NT; ++t) {
      if (t + 2 < NT) {
        int k2 = (t + 2) * BK;
#pragma unroll
        for (int cc = 0; cc < 4; ++cc)
          async16((char*)As[(t+2)%3] + dstA[cc], srcA[cc] + k2*2);
        br[t & 1] = *(const f32x2*)(gB + k2);
      }
      __builtin_amdgcn_sched_barrier(0);
      if (t + 1 < NT)
        *(unsigned*)((char*)Bs[(t+1) & 1] + wb) = pack2(br[(t+1) & 1]);
      {
        const char* Asc = (const char*)As[t % 3];
        const char* Bsc = (const char*)Bs[t & 1];
#pragma unroll
        for (int kk = 0; kk < 2; ++kk) {
          bf16x8 bf_ = *(const bf16x8*)(Bsc + boff[kk]);
#pragma unroll
          for (int mi = 0; mi < 2; ++mi) {
            bf16x8 a = *(const bf16x8*)(Asc + aoff[mi][kk]);
            acc[mi] = __builtin_amdgcn_mfma_f32_16x16x32_bf16(a, bf_, acc[mi], 0, 0, 0);
          }
        }
      }
      if (t + 1 < NT) lds_barrier();
    }

    // epilogue: direct scaled atomic scatter into out
#pragma unroll
    for (int mi = 0; mi < 2; ++mi)
#pragma unroll
      for (int j = 0; j < 4; ++j) {
        int p = m0 + wv*32 + mi*16 + lk*4 + j;
        if (p < c) {
          int   t = tok[e*TT + p];
          float w = wgt[e*TT + p];
          atomicAdd(&out[(size_t)t * HH + (n0 + lr)], w * acc[mi][j]);
        }
      }
  }
}

// ---------------------------------------------------------------- launch
extern "C" void kernel_launch(void* const* d_in, const int* in_sizes, int n_in,
                              void* d_out, int out_size, void* d_ws, size_t ws_size,
                              hipStream_t stream) {
  const float* hidden = (const float*)d_in[0];
  const int*   sel    = (const int*)d_in[1];
  const float* rw     = (const float*)d_in[2];
  const float* gup    = (const float*)d_in[3];
  const float* dwn    = (const float*)d_in[4];
  float* out = (float*)d_out;

  char* ws = (char*)d_ws;
  int*            cnt  = (int*)ws;                          // 1 KB pad
  int*            tok  = (int*)(ws + 1024);                 // 32 KB
  float*          wgt  = (float*)(ws + 33792);              // 32 KB
  unsigned short* X    = (unsigned short*)(ws + 66560);     // 16 MB
  unsigned short* Hb   = (unsigned short*)(ws + 16843776);  // 32 MB

  k_zero  <<<2048, 256, 0, stream>>>(out, cnt);
  k_build <<<8,    256, 0, stream>>>(sel, rw, cnt, tok, wgt);
  k_gather<<<dim3(TT, NL), 128, 0, stream>>>(hidden, cnt, tok, X);
  k_gemm1 <<<256, 512, 0, stream>>>(X, gup, cnt, Hb);
  k_gemm2 <<<256, 512, 0, stream>>>(Hb, dwn, cnt, tok, wgt, out);
}

// Round 12
// 60.565 us; speedup vs baseline: 3.1015x; 1.0186x over previous
//
#include <hip/hip_runtime.h>
#include <cstdint>
#include <cstddef>

#define TT  2048
#define HH  1024
#define FFN 2048
#define NL  4
#define BK  64
#define BM  256

typedef __attribute__((ext_vector_type(8))) short bf16x8;
typedef __attribute__((ext_vector_type(4))) unsigned short u16x4;
typedef __attribute__((ext_vector_type(4))) float f32x4;
typedef __attribute__((ext_vector_type(2))) float f32x2;

__device__ __forceinline__ unsigned short f2bf(float f) {
  unsigned u = __builtin_bit_cast(unsigned, f);
  u += 0x7FFFu + ((u >> 16) & 1u);           // RNE
  return (unsigned short)(u >> 16);
}

__device__ __forceinline__ bf16x8 pack8(f32x4 f0, f32x4 f1) {
  bf16x8 v;
  v[0] = (short)f2bf(f0[0]); v[1] = (short)f2bf(f0[1]);
  v[2] = (short)f2bf(f0[2]); v[3] = (short)f2bf(f0[3]);
  v[4] = (short)f2bf(f1[0]); v[5] = (short)f2bf(f1[1]);
  v[6] = (short)f2bf(f1[2]); v[7] = (short)f2bf(f1[3]);
  return v;
}

__device__ __forceinline__ unsigned pack2(f32x2 f) {
  return (unsigned)f2bf(f[0]) | ((unsigned)f2bf(f[1]) << 16);
}

__device__ __forceinline__ void async16(void* lds, const void* g) {
  __builtin_amdgcn_global_load_lds(
      (const __attribute__((address_space(1))) unsigned int*)g,
      (__attribute__((address_space(3))) unsigned int*)lds, 16, 0, 0);
}

// XOR swizzle inside [rows][64 bf16] (128 B rows); involution (rule 21).
__device__ __forceinline__ int swz(int b) { return b ^ (((b >> 7) & 7) << 4); }

// lgkm-only drain + raw barrier: counted global loads stay in flight (T4).
__device__ __forceinline__ void lds_barrier() {
  asm volatile("s_waitcnt lgkmcnt(0)" ::: "memory");
  __builtin_amdgcn_s_barrier();
}

// ---------------------------------------------------------------- zero
__global__ void k_zero(float* __restrict__ out, int* __restrict__ cnt) {
  int i = blockIdx.x * 256 + threadIdx.x;
  f32x4 z = {0.f, 0.f, 0.f, 0.f};
  reinterpret_cast<f32x4*>(out)[i] = z;
  if (i < NL) cnt[i] = 0;
}

// ---------------------------------------------------------------- routing lists
__global__ void k_build(const int* __restrict__ sel, const float* __restrict__ rw,
                        int* __restrict__ cnt, int* __restrict__ tok,
                        float* __restrict__ wgt) {
  int t = blockIdx.x * 256 + threadIdx.x;
  if (t >= TT) return;
  int   s0 = sel[t*4+0], s1 = sel[t*4+1], s2 = sel[t*4+2], s3 = sel[t*4+3];
  float r0 = rw[t*4+0],  r1 = rw[t*4+1],  r2 = rw[t*4+2],  r3 = rw[t*4+3];
#pragma unroll
  for (int i = 0; i < NL; ++i) {
    int eid = i * 8;
    float w = 0.f; bool m = false;
    if (s0 == eid) { w += r0; m = true; }
    if (s1 == eid) { w += r1; m = true; }
    if (s2 == eid) { w += r2; m = true; }
    if (s3 == eid) { w += r3; m = true; }
    if (m) {
      int p = atomicAdd(&cnt[i], 1);
      tok[i*TT + p] = t;
      wgt[i*TT + p] = w;
    }
  }
}

// ---------------------------------------------------------------- gather
__global__ void k_gather(const float* __restrict__ hidden, const int* __restrict__ cnt,
                         const int* __restrict__ tok, unsigned short* __restrict__ X) {
  int p = blockIdx.x, e = blockIdx.y;
  if (p >= cnt[e]) return;
  int t = tok[e*TT + p];
  const f32x4* src = reinterpret_cast<const f32x4*>(hidden + (size_t)t * HH);
  f32x4 a = src[threadIdx.x*2], b = src[threadIdx.x*2 + 1];
  reinterpret_cast<bf16x8*>(X + ((size_t)e*TT + p) * HH)[threadIdx.x] = pack8(a, b);
}

// ---------------------------------------------------------------- GEMM1
// R10 pipeline with ONE change: ds_write B(t+1) (the counted-vmcnt wait)
// moved AFTER the MFMA cluster, so compute overlaps the transfer tail.
__global__ __launch_bounds__(512) void k_gemm1(
    const unsigned short* __restrict__ X, const float* __restrict__ gup,
    const int* __restrict__ cnt, unsigned short* __restrict__ Hb) {
  int bid = blockIdx.x;
  int xcd = bid & 7;
  int e   = xcd >> 1;
  int idx = (bid >> 3) * 2 + (xcd & 1);   // 0..63
  int n0  = idx * 32;
  int c   = cnt[e];

  __shared__ alignas(16) unsigned short As[3][BM*BK];   // 3 x 32 KB
  __shared__ alignas(16) unsigned short Bs[2][64*BK];   // 2 x 8 KB

  int tid  = threadIdx.x;
  int lane = tid & 63, wv = tid >> 6;     // 8 waves
  int lr = lane & 15,  lk = lane >> 4;
  int wm = wv >> 1,    wn = wv & 1;       // 4M x 2N

  const unsigned short* Ab = X   + (size_t)e * TT * HH;
  const float*          Gb = gup + (size_t)e * 2 * FFN * HH;

  int arow[4], acol[4], dstA[4];
#pragma unroll
  for (int cc = 0; cc < 4; ++cc) {
    int chunk = wv * 4 + cc;
    int P = chunk * 1024 + lane * 16;
    arow[cc] = P >> 7;
    acol[cc] = (P & 127) ^ ((arow[cc] & 7) << 4);
    dstA[cc] = P;
  }

  int rb  = tid >> 3;                     // 0..63
  int cbf = (tid & 7) * 8;
  int grow = (rb < 32) ? (n0 + rb) : (FFN + n0 + rb - 32);
  const float* gB = Gb + (size_t)grow * HH + cbf;
  int wb = swz(rb * 128 + cbf * 2);

  int aoff[4][2], bgo[2], buo[2];
#pragma unroll
  for (int mi = 0; mi < 4; ++mi)
#pragma unroll
    for (int kk = 0; kk < 2; ++kk)
      aoff[mi][kk] = swz((wm*64 + mi*16 + lr) * 128 + kk*64 + lk*16);
#pragma unroll
  for (int kk = 0; kk < 2; ++kk) {
    bgo[kk] = swz((wn*16 + lr) * 128 + kk*64 + lk*16);
    buo[kk] = swz((32 + wn*16 + lr) * 128 + kk*64 + lk*16);
  }

  const int NT = HH / BK;   // 16

  for (int m0 = 0; m0 < c; m0 += BM) {
    __syncthreads();

    const char* srcA[4];
#pragma unroll
    for (int cc = 0; cc < 4; ++cc)
      srcA[cc] = (const char*)(Ab + (size_t)(m0 + arow[cc]) * HH) + acol[cc];

    f32x4 accg[4], accu[4];
    f32x4 z = {0.f, 0.f, 0.f, 0.f};
#pragma unroll
    for (int a = 0; a < 4; ++a) { accg[a] = z; accu[a] = z; }

    f32x4 br[2][2];

#pragma unroll
    for (int cc = 0; cc < 4; ++cc) async16((char*)As[0] + dstA[cc], srcA[cc]);
    br[0][0] = *(const f32x4*)(gB);
    br[0][1] = *(const f32x4*)(gB + 4);
    *(bf16x8*)((char*)Bs[0] + wb) = pack8(br[0][0], br[0][1]);
#pragma unroll
    for (int cc = 0; cc < 4; ++cc) async16((char*)As[1] + dstA[cc], srcA[cc] + BK*2);
    br[1][0] = *(const f32x4*)(gB + BK);
    br[1][1] = *(const f32x4*)(gB + BK + 4);
    lds_barrier();

#pragma unroll
    for (int t = 0; t < NT; ++t) {
      // 1) issue step t+2 (A -> ring, B -> regs)
      if (t + 2 < NT) {
        int k2 = (t + 2) * BK;
#pragma unroll
        for (int cc = 0; cc < 4; ++cc)
          async16((char*)As[(t+2)%3] + dstA[cc], srcA[cc] + k2*2);
        br[t & 1][0] = *(const f32x4*)(gB + k2);
        br[t & 1][1] = *(const f32x4*)(gB + k2 + 4);
      }
      __builtin_amdgcn_sched_barrier(0);
      // 2) compute step t (no global wait on this path)
      {
        const char* Asc = (const char*)As[t % 3];
        const char* Bsc = (const char*)Bs[t & 1];
#pragma unroll
        for (int kk = 0; kk < 2; ++kk) {
          bf16x8 bg = *(const bf16x8*)(Bsc + bgo[kk]);
          bf16x8 bu = *(const bf16x8*)(Bsc + buo[kk]);
#pragma unroll
          for (int mi = 0; mi < 4; ++mi) {
            bf16x8 a = *(const bf16x8*)(Asc + aoff[mi][kk]);
            accg[mi] = __builtin_amdgcn_mfma_f32_16x16x32_bf16(a, bg, accg[mi], 0, 0, 0);
            accu[mi] = __builtin_amdgcn_mfma_f32_16x16x32_bf16(a, bu, accu[mi], 0, 0, 0);
          }
        }
      }
      // 3) ds_write B(t+1): counted vmcnt(6) -> A(t+1) landed, t+2 in flight
      if (t + 1 < NT) {
        *(bf16x8*)((char*)Bs[(t+1) & 1] + wb) = pack8(br[(t+1) & 1][0], br[(t+1) & 1][1]);
        lds_barrier();
      }
    }

#pragma unroll
    for (int mi = 0; mi < 4; ++mi)
#pragma unroll
      for (int j = 0; j < 4; ++j) {
        int p = m0 + wm*64 + mi*16 + lk*4 + j;
        if (p < c) {
          float gv = accg[mi][j];
          float hv = (gv / (1.f + __expf(-gv))) * accu[mi][j];
          Hb[((size_t)e * TT + p) * FFN + (n0 + wn*16 + lr)] = f2bf(hv);
        }
      }
  }
}

// ---------------------------------------------------------------- GEMM2
// SK=1, BN=16, direct atomic scatter epilogue. Same reorder as gemm1.
__global__ __launch_bounds__(512) void k_gemm2(
    const unsigned short* __restrict__ Hb, const float* __restrict__ down,
    const int* __restrict__ cnt, const int* __restrict__ tok,
    const float* __restrict__ wgt, float* __restrict__ out) {
  int bid = blockIdx.x;
  int xcd = bid & 7;
  int e   = xcd >> 1;
  int idx = (bid >> 3) * 2 + (xcd & 1);   // 0..63
  int n0  = idx * 16;
  int c   = cnt[e];

  __shared__ alignas(16) unsigned short As[3][BM*BK];   // 3 x 32 KB
  __shared__ alignas(16) unsigned short Bs[2][16*BK];   // 2 x 2 KB

  int tid  = threadIdx.x;
  int lane = tid & 63, wv = tid >> 6;     // 8 waves, all M
  int lr = lane & 15,  lk = lane >> 4;

  const unsigned short* Ab = Hb   + (size_t)e * TT * FFN;
  const float*          Db = down + (size_t)e * HH * FFN;

  int arow[4], acol[4], dstA[4];
#pragma unroll
  for (int cc = 0; cc < 4; ++cc) {
    int chunk = wv * 4 + cc;
    int P = chunk * 1024 + lane * 16;
    arow[cc] = P >> 7;
    acol[cc] = (P & 127) ^ ((arow[cc] & 7) << 4);
    dstA[cc] = P;
  }

  int rb = tid >> 5;                      // 0..15
  int cw = tid & 31;                      // 2-float granule
  const float* gB = Db + (size_t)(n0 + rb) * FFN + cw*2;
  int wb = swz(rb * 128 + cw * 4);

  int aoff[2][2], boff[2];
#pragma unroll
  for (int mi = 0; mi < 2; ++mi)
#pragma unroll
    for (int kk = 0; kk < 2; ++kk)
      aoff[mi][kk] = swz((wv*32 + mi*16 + lr) * 128 + kk*64 + lk*16);
#pragma unroll
  for (int kk = 0; kk < 2; ++kk)
    boff[kk] = swz((lr) * 128 + kk*64 + lk*16);

  const int NT = FFN / BK;   // 32

  for (int m0 = 0; m0 < c; m0 += BM) {
    __syncthreads();

    const char* srcA[4];
#pragma unroll
    for (int cc = 0; cc < 4; ++cc)
      srcA[cc] = (const char*)(Ab + (size_t)(m0 + arow[cc]) * FFN) + acol[cc];

    f32x4 acc[2];
    f32x4 z = {0.f, 0.f, 0.f, 0.f};
    acc[0] = z; acc[1] = z;

    f32x2 br[2];

#pragma unroll
    for (int cc = 0; cc < 4; ++cc) async16((char*)As[0] + dstA[cc], srcA[cc]);
    br[0] = *(const f32x2*)(gB);
    *(unsigned*)((char*)Bs[0] + wb) = pack2(br[0]);
#pragma unroll
    for (int cc = 0; cc < 4; ++cc) async16((char*)As[1] + dstA[cc], srcA[cc] + BK*2);
    br[1] = *(const f32x2*)(gB + BK);
    lds_barrier();

#pragma unroll
    for (int t = 0; t < NT; ++t) {
      if (t + 2 < NT) {
        int k2 = (t + 2) * BK;
#pragma unroll
        for (int cc = 0; cc < 4; ++cc)
          async16((char*)As[(t+2)%3] + dstA[cc], srcA[cc] + k2*2);
        br[t & 1] = *(const f32x2*)(gB + k2);
      }
      __builtin_amdgcn_sched_barrier(0);
      {
        const char* Asc = (const char*)As[t % 3];
        const char* Bsc = (const char*)Bs[t & 1];
#pragma unroll
        for (int kk = 0; kk < 2; ++kk) {
          bf16x8 bf_ = *(const bf16x8*)(Bsc + boff[kk]);
#pragma unroll
          for (int mi = 0; mi < 2; ++mi) {
            bf16x8 a = *(const bf16x8*)(Asc + aoff[mi][kk]);
            acc[mi] = __builtin_amdgcn_mfma_f32_16x16x32_bf16(a, bf_, acc[mi], 0, 0, 0);
          }
        }
      }
      if (t + 1 < NT) {
        *(unsigned*)((char*)Bs[(t+1) & 1] + wb) = pack2(br[(t+1) & 1]);
        lds_barrier();
      }
    }

    // epilogue: direct scaled atomic scatter into out
#pragma unroll
    for (int mi = 0; mi < 2; ++mi)
#pragma unroll
      for (int j = 0; j < 4; ++j) {
        int p = m0 + wv*32 + mi*16 + lk*4 + j;
        if (p < c) {
          int   t = tok[e*TT + p];
          float w = wgt[e*TT + p];
          atomicAdd(&out[(size_t)t * HH + (n0 + lr)], w * acc[mi][j]);
        }
      }
  }
}

// ---------------------------------------------------------------- launch
extern "C" void kernel_launch(void* const* d_in, const int* in_sizes, int n_in,
                              void* d_out, int out_size, void* d_ws, size_t ws_size,
                              hipStream_t stream) {
  const float* hidden = (const float*)d_in[0];
  const int*   sel    = (const int*)d_in[1];
  const float* rw     = (const float*)d_in[2];
  const float* gup    = (const float*)d_in[3];
  const float* dwn    = (const float*)d_in[4];
  float* out = (float*)d_out;

  char* ws = (char*)d_ws;
  int*            cnt  = (int*)ws;                          // 1 KB pad
  int*            tok  = (int*)(ws + 1024);                 // 32 KB
  float*          wgt  = (float*)(ws + 33792);              // 32 KB
  unsigned short* X    = (unsigned short*)(ws + 66560);     // 16 MB
  unsigned short* Hb   = (unsigned short*)(ws + 16843776);  // 32 MB

  k_zero  <<<2048, 256, 0, stream>>>(out, cnt);
  k_build <<<8,    256, 0, stream>>>(sel, rw, cnt, tok, wgt);
  k_gather<<<dim3(TT, NL), 128, 0, stream>>>(hidden, cnt, tok, X);
  k_gemm1 <<<256, 512, 0, stream>>>(X, gup, cnt, Hb);
  k_gemm2 <<<256, 512, 0, stream>>>(Hb, dwn, cnt, tok, wgt, out);
}

// Round 13
// 58.195 us; speedup vs baseline: 3.2278x; 1.0407x over previous
//
#include <hip/hip_runtime.h>
#include <cstdint>
#include <cstddef>

#define TT  2048
#define HH  1024
#define FFN 2048
#define NL  4
#define BK  64
#define BM  256

typedef __attribute__((ext_vector_type(8))) short bf16x8;
typedef __attribute__((ext_vector_type(4))) float f32x4;
typedef __attribute__((ext_vector_type(2))) float f32x2;

__device__ __forceinline__ unsigned short f2bf(float f) {
  unsigned u = __builtin_bit_cast(unsigned, f);
  u += 0x7FFFu + ((u >> 16) & 1u);           // RNE
  return (unsigned short)(u >> 16);
}

__device__ __forceinline__ bf16x8 pack8(f32x4 f0, f32x4 f1) {
  bf16x8 v;
  v[0] = (short)f2bf(f0[0]); v[1] = (short)f2bf(f0[1]);
  v[2] = (short)f2bf(f0[2]); v[3] = (short)f2bf(f0[3]);
  v[4] = (short)f2bf(f1[0]); v[5] = (short)f2bf(f1[1]);
  v[6] = (short)f2bf(f1[2]); v[7] = (short)f2bf(f1[3]);
  return v;
}

__device__ __forceinline__ unsigned pack2(f32x2 f) {
  return (unsigned)f2bf(f[0]) | ((unsigned)f2bf(f[1]) << 16);
}

__device__ __forceinline__ void async16(void* lds, const void* g) {
  __builtin_amdgcn_global_load_lds(
      (const __attribute__((address_space(1))) unsigned int*)g,
      (__attribute__((address_space(3))) unsigned int*)lds, 16, 0, 0);
}

// XOR swizzle inside [rows][64 bf16] (128 B rows); involution (rule 21).
__device__ __forceinline__ int swz(int b) { return b ^ (((b >> 7) & 7) << 4); }

// lgkm-only drain + raw barrier: counted global loads stay in flight (T4).
__device__ __forceinline__ void lds_barrier() {
  asm volatile("s_waitcnt lgkmcnt(0)" ::: "memory");
  __builtin_amdgcn_s_barrier();
}

// ---------------------------------------------------------------- zero
__global__ void k_zero(float* __restrict__ out, int* __restrict__ cnt) {
  int i = blockIdx.x * 256 + threadIdx.x;
  f32x4 z = {0.f, 0.f, 0.f, 0.f};
  reinterpret_cast<f32x4*>(out)[i] = z;
  if (i < NL) cnt[i] = 0;
}

// ---------------------------------------------------------------- routing lists
__global__ void k_build(const int* __restrict__ sel, const float* __restrict__ rw,
                        int* __restrict__ cnt, int* __restrict__ tok,
                        float* __restrict__ wgt) {
  int t = blockIdx.x * 256 + threadIdx.x;
  if (t >= TT) return;
  int   s0 = sel[t*4+0], s1 = sel[t*4+1], s2 = sel[t*4+2], s3 = sel[t*4+3];
  float r0 = rw[t*4+0],  r1 = rw[t*4+1],  r2 = rw[t*4+2],  r3 = rw[t*4+3];
#pragma unroll
  for (int i = 0; i < NL; ++i) {
    int eid = i * 8;
    float w = 0.f; bool m = false;
    if (s0 == eid) { w += r0; m = true; }
    if (s1 == eid) { w += r1; m = true; }
    if (s2 == eid) { w += r2; m = true; }
    if (s3 == eid) { w += r3; m = true; }
    if (m) {
      int p = atomicAdd(&cnt[i], 1);
      tok[i*TT + p] = t;
      wgt[i*TT + p] = w;
    }
  }
}

// ---------------------------------------------------------------- gather
__global__ void k_gather(const float* __restrict__ hidden, const int* __restrict__ cnt,
                         const int* __restrict__ tok, unsigned short* __restrict__ X) {
  int p = blockIdx.x, e = blockIdx.y;
  if (p >= cnt[e]) return;
  int t = tok[e*TT + p];
  const f32x4* src = reinterpret_cast<const f32x4*>(hidden + (size_t)t * HH);
  f32x4 a = src[threadIdx.x*2], b = src[threadIdx.x*2 + 1];
  reinterpret_cast<bf16x8*>(X + ((size_t)e*TT + p) * HH)[threadIdx.x] = pack8(a, b);
}

// ---------------------------------------------------------------- GEMM1
// D=3 pipeline: 4-slot A-LDS ring (global_load_lds), 3-slot B reg rotation.
// At step t: issue A/B(t+3); compute t; ds_write B(t+1) (derived vmcnt(12)
// drains through A(t+1)/B(t+1), keeps 2 steps in flight); lgkm-only barrier.
__global__ __launch_bounds__(512) void k_gemm1(
    const unsigned short* __restrict__ X, const float* __restrict__ gup,
    const int* __restrict__ cnt, unsigned short* __restrict__ Hb) {
  int bid = blockIdx.x;
  int xcd = bid & 7;
  int e   = xcd >> 1;
  int idx = (bid >> 3) * 2 + (xcd & 1);   // 0..63
  int n0  = idx * 32;
  int c   = cnt[e];

  __shared__ alignas(16) unsigned short As[4][BM*BK];   // 4 x 32 KB
  __shared__ alignas(16) unsigned short Bs[2][64*BK];   // 2 x 8 KB

  int tid  = threadIdx.x;
  int lane = tid & 63, wv = tid >> 6;     // 8 waves
  int lr = lane & 15,  lk = lane >> 4;
  int wm = wv >> 1,    wn = wv & 1;       // 4M x 2N

  const unsigned short* Ab = X   + (size_t)e * TT * HH;
  const float*          Gb = gup + (size_t)e * 2 * FFN * HH;

  int arow[4], acol[4], dstA[4];
#pragma unroll
  for (int cc = 0; cc < 4; ++cc) {
    int chunk = wv * 4 + cc;
    int P = chunk * 1024 + lane * 16;
    arow[cc] = P >> 7;
    acol[cc] = (P & 127) ^ ((arow[cc] & 7) << 4);
    dstA[cc] = P;
  }

  int rb  = tid >> 3;                     // 0..63
  int cbf = (tid & 7) * 8;
  int grow = (rb < 32) ? (n0 + rb) : (FFN + n0 + rb - 32);
  const float* gB = Gb + (size_t)grow * HH + cbf;
  int wb = swz(rb * 128 + cbf * 2);

  int aoff[4][2], bgo[2], buo[2];
#pragma unroll
  for (int mi = 0; mi < 4; ++mi)
#pragma unroll
    for (int kk = 0; kk < 2; ++kk)
      aoff[mi][kk] = swz((wm*64 + mi*16 + lr) * 128 + kk*64 + lk*16);
#pragma unroll
  for (int kk = 0; kk < 2; ++kk) {
    bgo[kk] = swz((wn*16 + lr) * 128 + kk*64 + lk*16);
    buo[kk] = swz((32 + wn*16 + lr) * 128 + kk*64 + lk*16);
  }

  const int NT = HH / BK;   // 16

  for (int m0 = 0; m0 < c; m0 += BM) {
    __syncthreads();

    const char* srcA[4];
#pragma unroll
    for (int cc = 0; cc < 4; ++cc)
      srcA[cc] = (const char*)(Ab + (size_t)(m0 + arow[cc]) * HH) + acol[cc];

    f32x4 accg[4], accu[4];
    f32x4 z = {0.f, 0.f, 0.f, 0.f};
#pragma unroll
    for (int a = 0; a < 4; ++a) { accg[a] = z; accu[a] = z; }

    f32x4 br[3][2];

    // ---- prologue: B(0) regs; A(0),A(1),A(2) issue; B(1),B(2) regs
    br[0][0] = *(const f32x4*)(gB);
    br[0][1] = *(const f32x4*)(gB + 4);
#pragma unroll
    for (int cc = 0; cc < 4; ++cc) async16((char*)As[0] + dstA[cc], srcA[cc]);
#pragma unroll
    for (int cc = 0; cc < 4; ++cc) async16((char*)As[1] + dstA[cc], srcA[cc] + BK*2);
#pragma unroll
    for (int cc = 0; cc < 4; ++cc) async16((char*)As[2] + dstA[cc], srcA[cc] + 2*BK*2);
    br[1][0] = *(const f32x4*)(gB + BK);
    br[1][1] = *(const f32x4*)(gB + BK + 4);
    br[2][0] = *(const f32x4*)(gB + 2*BK);
    br[2][1] = *(const f32x4*)(gB + 2*BK + 4);
    *(bf16x8*)((char*)Bs[0] + wb) = pack8(br[0][0], br[0][1]);
    asm volatile("s_waitcnt vmcnt(12)" ::: "memory");   // A(0) landed; A(1..2),B(1..2) fly
    lds_barrier();

#pragma unroll
    for (int t = 0; t < NT; ++t) {
      // 1) issue step t+3
      if (t + 3 < NT) {
        int k3 = (t + 3) * BK;
#pragma unroll
        for (int cc = 0; cc < 4; ++cc)
          async16((char*)As[(t+3) & 3] + dstA[cc], srcA[cc] + k3*2);
        br[(t+3) % 3][0] = *(const f32x4*)(gB + k3);
        br[(t+3) % 3][1] = *(const f32x4*)(gB + k3 + 4);
      }
      __builtin_amdgcn_sched_barrier(0);
      // 2) compute step t
      {
        const char* Asc = (const char*)As[t & 3];
        const char* Bsc = (const char*)Bs[t & 1];
#pragma unroll
        for (int kk = 0; kk < 2; ++kk) {
          bf16x8 bg = *(const bf16x8*)(Bsc + bgo[kk]);
          bf16x8 bu = *(const bf16x8*)(Bsc + buo[kk]);
#pragma unroll
          for (int mi = 0; mi < 4; ++mi) {
            bf16x8 a = *(const bf16x8*)(Asc + aoff[mi][kk]);
            accg[mi] = __builtin_amdgcn_mfma_f32_16x16x32_bf16(a, bg, accg[mi], 0, 0, 0);
            accu[mi] = __builtin_amdgcn_mfma_f32_16x16x32_bf16(a, bu, accu[mi], 0, 0, 0);
          }
        }
      }
      // 3) ds_write B(t+1): derived wait drains A(t+1)/B(t+1); 2 steps in flight
      if (t + 1 < NT) {
        *(bf16x8*)((char*)Bs[(t+1) & 1] + wb) =
            pack8(br[(t+1) % 3][0], br[(t+1) % 3][1]);
        lds_barrier();
      }
    }

#pragma unroll
    for (int mi = 0; mi < 4; ++mi)
#pragma unroll
      for (int j = 0; j < 4; ++j) {
        int p = m0 + wm*64 + mi*16 + lk*4 + j;
        if (p < c) {
          float gv = accg[mi][j];
          float hv = (gv / (1.f + __expf(-gv))) * accu[mi][j];
          Hb[((size_t)e * TT + p) * FFN + (n0 + wn*16 + lr)] = f2bf(hv);
        }
      }
  }
}

// ---------------------------------------------------------------- GEMM2
// D=3, SK=1, BN=16, direct atomic scatter epilogue.
__global__ __launch_bounds__(512) void k_gemm2(
    const unsigned short* __restrict__ Hb, const float* __restrict__ down,
    const int* __restrict__ cnt, const int* __restrict__ tok,
    const float* __restrict__ wgt, float* __restrict__ out) {
  int bid = blockIdx.x;
  int xcd = bid & 7;
  int e   = xcd >> 1;
  int idx = (bid >> 3) * 2 + (xcd & 1);   // 0..63
  int n0  = idx * 16;
  int c   = cnt[e];

  __shared__ alignas(16) unsigned short As[4][BM*BK];   // 4 x 32 KB
  __shared__ alignas(16) unsigned short Bs[2][16*BK];   // 2 x 2 KB

  int tid  = threadIdx.x;
  int lane = tid & 63, wv = tid >> 6;     // 8 waves, all M
  int lr = lane & 15,  lk = lane >> 4;

  const unsigned short* Ab = Hb   + (size_t)e * TT * FFN;
  const float*          Db = down + (size_t)e * HH * FFN;

  int arow[4], acol[4], dstA[4];
#pragma unroll
  for (int cc = 0; cc < 4; ++cc) {
    int chunk = wv * 4 + cc;
    int P = chunk * 1024 + lane * 16;
    arow[cc] = P >> 7;
    acol[cc] = (P & 127) ^ ((arow[cc] & 7) << 4);
    dstA[cc] = P;
  }

  int rb = tid >> 5;                      // 0..15
  int cw = tid & 31;                      // 2-float granule
  const float* gB = Db + (size_t)(n0 + rb) * FFN + cw*2;
  int wb = swz(rb * 128 + cw * 4);

  int aoff[2][2], boff[2];
#pragma unroll
  for (int mi = 0; mi < 2; ++mi)
#pragma unroll
    for (int kk = 0; kk < 2; ++kk)
      aoff[mi][kk] = swz((wv*32 + mi*16 + lr) * 128 + kk*64 + lk*16);
#pragma unroll
  for (int kk = 0; kk < 2; ++kk)
    boff[kk] = swz((lr) * 128 + kk*64 + lk*16);

  const int NT = FFN / BK;   // 32

  for (int m0 = 0; m0 < c; m0 += BM) {
    __syncthreads();

    const char* srcA[4];
#pragma unroll
    for (int cc = 0; cc < 4; ++cc)
      srcA[cc] = (const char*)(Ab + (size_t)(m0 + arow[cc]) * FFN) + acol[cc];

    f32x4 acc[2];
    f32x4 z = {0.f, 0.f, 0.f, 0.f};
    acc[0] = z; acc[1] = z;

    f32x2 br[3];

    // ---- prologue
    br[0] = *(const f32x2*)(gB);
#pragma unroll
    for (int cc = 0; cc < 4; ++cc) async16((char*)As[0] + dstA[cc], srcA[cc]);
#pragma unroll
    for (int cc = 0; cc < 4; ++cc) async16((char*)As[1] + dstA[cc], srcA[cc] + BK*2);
#pragma unroll
    for (int cc = 0; cc < 4; ++cc) async16((char*)As[2] + dstA[cc], srcA[cc] + 2*BK*2);
    br[1] = *(const f32x2*)(gB + BK);
    br[2] = *(const f32x2*)(gB + 2*BK);
    *(unsigned*)((char*)Bs[0] + wb) = pack2(br[0]);
    asm volatile("s_waitcnt vmcnt(10)" ::: "memory");   // A(0) landed
    lds_barrier();

#pragma unroll
    for (int t = 0; t < NT; ++t) {
      if (t + 3 < NT) {
        int k3 = (t + 3) * BK;
#pragma unroll
        for (int cc = 0; cc < 4; ++cc)
          async16((char*)As[(t+3) & 3] + dstA[cc], srcA[cc] + k3*2);
        br[(t+3) % 3] = *(const f32x2*)(gB + k3);
      }
      __builtin_amdgcn_sched_barrier(0);
      {
        const char* Asc = (const char*)As[t & 3];
        const char* Bsc = (const char*)Bs[t & 1];
#pragma unroll
        for (int kk = 0; kk < 2; ++kk) {
          bf16x8 bf_ = *(const bf16x8*)(Bsc + boff[kk]);
#pragma unroll
          for (int mi = 0; mi < 2; ++mi) {
            bf16x8 a = *(const bf16x8*)(Asc + aoff[mi][kk]);
            acc[mi] = __builtin_amdgcn_mfma_f32_16x16x32_bf16(a, bf_, acc[mi], 0, 0, 0);
          }
        }
      }
      if (t + 1 < NT) {
        *(unsigned*)((char*)Bs[(t+1) & 1] + wb) = pack2(br[(t+1) % 3]);
        lds_barrier();
      }
    }

    // epilogue: direct scaled atomic scatter into out
#pragma unroll
    for (int mi = 0; mi < 2; ++mi)
#pragma unroll
      for (int j = 0; j < 4; ++j) {
        int p = m0 + wv*32 + mi*16 + lk*4 + j;
        if (p < c) {
          int   t = tok[e*TT + p];
          float w = wgt[e*TT + p];
          atomicAdd(&out[(size_t)t * HH + (n0 + lr)], w * acc[mi][j]);
        }
      }
  }
}

// ---------------------------------------------------------------- launch
extern "C" void kernel_launch(void* const* d_in, const int* in_sizes, int n_in,
                              void* d_out, int out_size, void* d_ws, size_t ws_size,
                              hipStream_t stream) {
  const float* hidden = (const float*)d_in[0];
  const int*   sel    = (const int*)d_in[1];
  const float* rw     = (const float*)d_in[2];
  const float* gup    = (const float*)d_in[3];
  const float* dwn    = (const float*)d_in[4];
  float* out = (float*)d_out;

  char* ws = (char*)d_ws;
  int*            cnt  = (int*)ws;                          // 1 KB pad
  int*            tok  = (int*)(ws + 1024);                 // 32 KB
  float*          wgt  = (float*)(ws + 33792);              // 32 KB
  unsigned short* X    = (unsigned short*)(ws + 66560);     // 16 MB
  unsigned short* Hb   = (unsigned short*)(ws + 16843776);  // 32 MB

  k_zero  <<<2048, 256, 0, stream>>>(out, cnt);
  k_build <<<8,    256, 0, stream>>>(sel, rw, cnt, tok, wgt);
  k_gather<<<dim3(TT, NL), 128, 0, stream>>>(hidden, cnt, tok, X);
  k_gemm1 <<<256, 512, 0, stream>>>(X, gup, cnt, Hb);
  k_gemm2 <<<256, 512, 0, stream>>>(Hb, dwn, cnt, tok, wgt, out);
}